// Round 3
// 94.469 us; speedup vs baseline: 1.0694x; 1.0694x over previous
//
#include <hip/hip_runtime.h>
#include <cstdint>

#define DD   256   // embedding dim
#define NS   320   // n_support
#define NQ   2048  // n_query
#define NWAY 20
#define QTP  8     // queries/supports per proj block
#define QT   4     // queries per matchnet block
#define NQB  (NQ / QTP)  // 256 query-proj blocks
#define NSB  (NS / QTP)  // 40 support-proj blocks
#define CMAX 64    // max supports per class (labels random, ~16 each)

typedef _Float16 f16x2 __attribute__((ext_vector_type(2)));

__device__ __forceinline__ f16x2 u2f(unsigned u) {
  f16x2 f; __builtin_memcpy(&f, &u, 4); return f;
}

// acc += dot(relu(q + s), w) over a d-pair: v_pk_add_f16 + v_pk_max_f16 +
// v_dot2_f32_f16 = 3 VALU per 2 elements (vs 6 in f32). f32 accumulate.
__device__ __forceinline__ float relu_dot2(f16x2 q, f16x2 s, f16x2 w, float c) {
  f16x2 h = q + s;
  const f16x2 z = {(_Float16)0.f, (_Float16)0.f};
  h = __builtin_elementwise_max(h, z);
#if __has_builtin(__builtin_amdgcn_fdot2)
  return __builtin_amdgcn_fdot2(h, w, c, false);
#else
  return c + (float)h.x * (float)w.x + (float)h.y * (float)w.y;
#endif
}

// Fused projections, k-split-4 across 1024 threads (d = t&255, kq = t>>8).
// W1 column loads coalesced b32; qe/sup row loads wave-uniform -> s_load.
// f32 accumulate; epilogue converts to f16 for the matchnet datapath:
//   qph  [q][d]  f16 row-major (consumed via s_load_dwordx4 -> 4 d-pairs)
//   spb2 [d/2][s] f16x2 d-pair-major (consumed as coalesced b32 per lane)
//   w2h  [d]     f16 (block 0 converts W2 once)
__global__ __launch_bounds__(1024) void proj_kernel(
    const float* __restrict__ sup, const float* __restrict__ qe,
    const float* __restrict__ W1, const float* __restrict__ b1,
    const float* __restrict__ W2,
    _Float16* __restrict__ qph, f16x2* __restrict__ spb2,
    _Float16* __restrict__ w2h) {
  __shared__ float pacc[3][QTP][DD];   // 24 KB k-combine buffer
  const int t  = threadIdx.x;
  const int d  = t & 255;
  const int kq = t >> 8;               // 0..3, wave-uniform
  const int b  = blockIdx.x;
  const bool isQ = (b < NQB);
  const int r0 = isQ ? b * QTP : (b - NQB) * QTP;
  const float* src   = isQ ? qe : sup;
  const float* wcol  = W1 + (isQ ? 0 : (size_t)DD * DD) + (size_t)(kq * 64) * DD + d;
  const float* rbase = src + __builtin_amdgcn_readfirstlane(r0 * DD + kq * 64);

  if (b == 0 && kq == 0) w2h[d] = (_Float16)W2[d];   // one-time W2 -> f16

  float acc[QTP] = {0.f, 0.f, 0.f, 0.f, 0.f, 0.f, 0.f, 0.f};
#pragma unroll 8
  for (int k = 0; k < 64; ++k) {
    const float wv = wcol[(size_t)k * DD];       // coalesced, L2-resident
#pragma unroll
    for (int i = 0; i < QTP; ++i)
      acc[i] += rbase[i * DD + k] * wv;          // uniform -> s_load (SMEM pipe)
  }
  if (kq) {
#pragma unroll
    for (int i = 0; i < QTP; ++i) pacc[kq - 1][i][d] = acc[i];
  }
  __syncthreads();
  if (kq == 0) {
    if (isQ) {
#pragma unroll
      for (int i = 0; i < QTP; ++i) {
        const float v = acc[i] + pacc[0][i][d] + pacc[1][i][d] + pacc[2][i][d];
        qph[(size_t)(r0 + i) * DD + d] = (_Float16)v;   // coalesced b16
      }
    } else {
      const float bb = b1[d];
#pragma unroll
      for (int i = 0; i < QTP; ++i) {
        const float v = acc[i] + pacc[0][i][d] + pacc[1][i][d] + pacc[2][i][d] + bb;
        const float vh = __shfl_down(v, 1);      // lane 2k gets d=2k+1's value
        if (!(d & 1)) {
          f16x2 p = {(_Float16)v, (_Float16)vh}; // .x = even d, .y = odd d
          spb2[(size_t)(d >> 1) * NS + (r0 + i)] = p;   // tiny volume, 40 blocks
        }
      }
    }
  }
}

// matchnet: 512 blocks x 640 threads (10 waves, 2 blocks/CU -> 5 waves/SIMD).
// Waves 0-4: s=t, d in [0,128); waves 5-9: same supports, d in [128,256).
// f16 packed datapath: per 8 d's per query = 4x{pk_add, pk_max, dot2} = 12 VALU
// (halved vs f32). sv coalesced b32 (VMEM, L2); q/W2 wave-uniform -> s_load.
// Epilogue (f32): combine halves, block softmax, per-class sums via label
// index lists (classes NOT balanced).
__global__ __launch_bounds__(640) void matchnet_kernel(
    const _Float16* __restrict__ qph, const f16x2* __restrict__ spb2,
    const _Float16* __restrict__ w2h, const int* __restrict__ labels,
    float* __restrict__ out) {
  __shared__ float wexp[QT][NS];        // d-half partials, then exp weights
  __shared__ float wm[5];
  __shared__ float csum[QT * NWAY];
  __shared__ int   ccnt[NWAY];
  __shared__ short cidx[NWAY * CMAX];
  const int t    = threadIdx.x;
  const int q0   = blockIdx.x * QT;
  const int half = t / NS;              // wave-uniform (NS = 5 waves)
  const int s    = t - half * NS;

  if (t < NWAY) ccnt[t] = 0;
  __syncthreads();
  if (!half) {                          // build per-class index lists
    const int lab  = labels[s];
    const int slot = atomicAdd(&ccnt[lab], 1);
    cidx[lab * CMAX + slot] = (short)s;
  }

  const int d0 = half * (DD / 2);
  const _Float16* qb = qph + __builtin_amdgcn_readfirstlane(q0 * DD + d0);
  const _Float16* wb = w2h + d0;
  const f16x2*    sb = spb2 + (size_t)(d0 >> 1) * NS + s;

  float acc[QT] = {0.f, 0.f, 0.f, 0.f};
#pragma unroll 2
  for (int dd = 0; dd < DD / 2; dd += 8) {       // 8 d's = 4 pairs per step
    const int dp = dd >> 1;
    const f16x2 sv0 = sb[(dp + 0) * NS];         // coalesced b32, L1/L2
    const f16x2 sv1 = sb[(dp + 1) * NS];
    const f16x2 sv2 = sb[(dp + 2) * NS];
    const f16x2 sv3 = sb[(dp + 3) * NS];
    const uint4 wv = *reinterpret_cast<const uint4*>(wb + dd);  // s_load_dwordx4
    const f16x2 w0 = u2f(wv.x), w1 = u2f(wv.y), w2 = u2f(wv.z), w3 = u2f(wv.w);
#pragma unroll
    for (int i = 0; i < QT; ++i) {
      const uint4 qv = *reinterpret_cast<const uint4*>(qb + i * DD + dd);  // s_load
      float a = acc[i];
      a = relu_dot2(u2f(qv.x), sv0, w0, a);
      a = relu_dot2(u2f(qv.y), sv1, w1, a);
      a = relu_dot2(u2f(qv.z), sv2, w2, a);
      a = relu_dot2(u2f(qv.w), sv3, w3, a);
      acc[i] = a;
    }
  }

  // Combine d-halves.
  if (half) {
#pragma unroll
    for (int i = 0; i < QT; ++i) wexp[i][s] = acc[i];
  }
  __syncthreads();
  float m = -1e30f;
  if (!half) {
#pragma unroll
    for (int i = 0; i < QT; ++i) { acc[i] += wexp[i][s]; m = fmaxf(m, acc[i]); }
#pragma unroll
    for (int off = 32; off > 0; off >>= 1)
      m = fmaxf(m, __shfl_xor(m, off));
    if ((t & 63) == 0) wm[t >> 6] = m;
  }
  __syncthreads();
  if (!half) {
    const float M = fmaxf(fmaxf(fmaxf(wm[0], wm[1]), fmaxf(wm[2], wm[3])), wm[4]);
#pragma unroll
    for (int i = 0; i < QT; ++i) wexp[i][s] = __expf(acc[i] - M);
  }
  __syncthreads();
  // Per-(query,class) sums over that class's supports (variable count).
  if (t < QT * NWAY) {
    const int i = t / NWAY, c = t - i * NWAY;
    const int n = ccnt[c];
    float sum = 0.f;
    for (int j = 0; j < n; ++j) sum += wexp[i][cidx[c * CMAX + j]];
    csum[t] = sum;
  }
  __syncthreads();
  if (t < QT * NWAY) {
    const int i = t / NWAY, c = t - i * NWAY;
    float tot = 0.f;
#pragma unroll
    for (int j = 0; j < NWAY; ++j) tot += csum[i * NWAY + j];
    out[(size_t)(q0 + i) * NWAY + c] = csum[t] / tot;
  }
}

extern "C" void kernel_launch(void* const* d_in, const int* in_sizes, int n_in,
                              void* d_out, int out_size, void* d_ws, size_t ws_size,
                              hipStream_t stream) {
  const float* sup = (const float*)d_in[0];   // [320,256]
  const float* qe  = (const float*)d_in[1];   // [2048,256]
  const int*   lab = (const int*)d_in[2];     // [320] int32
  const float* W1  = (const float*)d_in[3];   // [512,256]
  const float* b1  = (const float*)d_in[4];   // [256]
  const float* W2  = (const float*)d_in[5];   // [256]
  // b2 (d_in[6]) softmax-invariant -> unused. n_way/n_shot hardcoded.
  float* out = (float*)d_out;                 // [2048,20]
  char* ws = (char*)d_ws;
  f16x2*    spb2 = (f16x2*)ws;                         // 128*320*4B = 160 KB
  _Float16* qph  = (_Float16*)(ws + 256 * 1024);       // 2048*256*2B = 1 MB
  _Float16* w2h  = (_Float16*)(ws + 256 * 1024 + 1024 * 1024);  // 512 B

  proj_kernel<<<NQB + NSB, 1024, 0, stream>>>(sup, qe, W1, b1, W2, qph, spb2, w2h);
  matchnet_kernel<<<NQ / QT, 640, 0, stream>>>(qph, spb2, w2h, lab, out);
}